// Round 1
// baseline (126.420 us; speedup 1.0000x reference)
//
#include <hip/hip_runtime.h>
#include <hip/hip_bf16.h>

typedef __attribute__((ext_vector_type(8))) short short8;
typedef __attribute__((ext_vector_type(8))) unsigned short ushort8;
typedef __attribute__((ext_vector_type(4))) float f32x4;

#define NB 2
#define NH 12
#define NL 1024
#define NT 1024
#define ND 64
#define NCH 36
#define DIM 768

// round-to-nearest-even f32 -> bf16 bits (inputs finite; no NaN handling needed)
static __device__ __forceinline__ unsigned short f2bf(float x) {
  union { float f; unsigned int u; } c; c.f = x;
  unsigned int r = c.u + 0x7fffu + ((c.u >> 16) & 1u);
  return (unsigned short)(r >> 16);
}

// ---------------------------------------------------------------------------
// K1: channel-fuse (36 -> 12) + softmax over T, write attn as bf16.
// One block per (b, l): every score element is read exactly once.
// fuse_b is intentionally ignored: softmax(x + c) == softmax(x) for a
// per-row constant c (fuse_b[o] is constant over the softmax axis t).
// ---------------------------------------------------------------------------
__global__ __launch_bounds__(256) void k_fuse_softmax(
    const float* __restrict__ s0, const float* __restrict__ s1,
    const float* __restrict__ s2, const float* __restrict__ fw,
    unsigned short* __restrict__ attn)
{
  __shared__ float wS[NCH][NH];     // wS[c][h] = fuse_w[h][c]
  __shared__ float fused[NH][NT];   // 48 KiB
  const int tid = threadIdx.x;
  const int b = blockIdx.x >> 10;
  const int l = blockIdx.x & 1023;

  for (int i = tid; i < NCH * NH; i += 256) {
    int h = i % NH, c = i / NH;
    wS[c][h] = fw[h * NCH + c];
  }
  __syncthreads();

  float acc[NH][4];
#pragma unroll
  for (int h = 0; h < NH; ++h) {
    acc[h][0] = 0.f; acc[h][1] = 0.f; acc[h][2] = 0.f; acc[h][3] = 0.f;
  }

  const int t0 = tid * 4;  // each thread owns 4 contiguous t
  const size_t base = (size_t)b * NH * NL * NT + (size_t)l * NT + t0;
  const float* sp0 = s0 + base;
  const float* sp1 = s1 + base;
  const float* sp2 = s2 + base;
#pragma unroll
  for (int g = 0; g < 3; ++g) {
    const float* p = (g == 0) ? sp0 : (g == 1) ? sp1 : sp2;
#pragma unroll
    for (int ch = 0; ch < NH; ++ch) {
      float4 sv = *(const float4*)(p + (size_t)ch * NL * NT);
#pragma unroll
      for (int h = 0; h < NH; ++h) {
        float w = wS[g * NH + ch][h];
        acc[h][0] = fmaf(w, sv.x, acc[h][0]);
        acc[h][1] = fmaf(w, sv.y, acc[h][1]);
        acc[h][2] = fmaf(w, sv.z, acc[h][2]);
        acc[h][3] = fmaf(w, sv.w, acc[h][3]);
      }
    }
  }
#pragma unroll
  for (int h = 0; h < NH; ++h) {
    *(float4*)&fused[h][t0] = make_float4(acc[h][0], acc[h][1], acc[h][2], acc[h][3]);
  }
  __syncthreads();

  // softmax: 4 waves x 3 heads each, wave-parallel reduce over 64 lanes
  const int wv = tid >> 6, lane = tid & 63;
  for (int i = 0; i < 3; ++i) {
    const int h = wv * 3 + i;
    float v[16];
    float m = -3.0e38f;
#pragma unroll
    for (int k = 0; k < 16; ++k) {
      v[k] = fused[h][lane + 64 * k];
      m = fmaxf(m, v[k]);
    }
#pragma unroll
    for (int off = 32; off > 0; off >>= 1) m = fmaxf(m, __shfl_xor(m, off));
    float s = 0.f;
#pragma unroll
    for (int k = 0; k < 16; ++k) { v[k] = __expf(v[k] - m); s += v[k]; }
#pragma unroll
    for (int off = 32; off > 0; off >>= 1) s += __shfl_xor(s, off);
    const float inv = 1.0f / s;
    unsigned short* op = attn + ((size_t)(b * NH + h) * NL + l) * NT;
#pragma unroll
    for (int k = 0; k < 16; ++k) op[lane + 64 * k] = f2bf(v[k] * inv);
  }
}

// ---------------------------------------------------------------------------
// K2a: v (B,H,T,D) f32  ->  vT (B,H,D,T) bf16, via LDS tile transpose.
// Makes the PV B-fragment a contiguous-k 16B load.
// ---------------------------------------------------------------------------
__global__ __launch_bounds__(256) void k_transpose_v(
    const float* __restrict__ v, unsigned short* __restrict__ vT)
{
  __shared__ float vS[128][65];  // +1 pad breaks column-read conflicts
  const int tid = threadIdx.x;
  const int tt = blockIdx.x;   // t-tile of 128
  const int h = blockIdx.y, b = blockIdx.z;
  const int t0 = tt * 128;
  const float* vp = v + ((size_t)(b * NH + h) * NT + t0) * ND;
#pragma unroll
  for (int r = 0; r < 8; ++r) {
    int f = tid + r * 256;            // 2048 float4 chunks
    int t = f >> 4, d4 = (f & 15) * 4;
    float4 x = *(const float4*)(vp + (size_t)t * ND + d4);
    vS[t][d4 + 0] = x.x; vS[t][d4 + 1] = x.y;
    vS[t][d4 + 2] = x.z; vS[t][d4 + 3] = x.w;
  }
  __syncthreads();
  unsigned short* op = vT + (size_t)(b * NH + h) * ND * NT;
#pragma unroll
  for (int r = 0; r < 4; ++r) {
    int c = tid + r * 256;            // 1024 ushort8 chunks
    int d = c >> 4, tl = (c & 15) * 8;
    ushort8 u;
#pragma unroll
    for (int j = 0; j < 8; ++j) u[j] = f2bf(vS[tl + j][d]);
    *(ushort8*)(op + (size_t)d * NT + t0 + tl) = u;
  }
}

// ---------------------------------------------------------------------------
// K2: PV GEMM  x[b,h,l,:] = attn[b,h,l,:] @ v[b,h,:,:]  via bf16 MFMA.
// MFMA 16x16x32 fragment layout (per guide; forced by ref-checked m92/m97
// which feed 8 *contiguous* k per lane via ds_read_b128):
//   A: row = lane&15, k = 8*(lane>>4)+e   (e=0..7, one 16B load)
//   B: col = lane&15, k = 8*(lane>>4)+e   (16B from k-contiguous vT row)
//   C/D: col = lane&15, row = (lane>>4)*4 + reg   [measured m89/m91]
// LDS vS stride 136 ushorts: b128 bank-start = 4*((lane&15)+(lane>>4))%32,
// uniform 8 lanes per start == contiguous-b128 distribution -> conflict-free.
// ---------------------------------------------------------------------------
__global__ __launch_bounds__(128) void k_pv(
    const unsigned short* __restrict__ attn,
    const unsigned short* __restrict__ vT,
    unsigned short* __restrict__ xb)
{
  __shared__ unsigned short vS[64][136];
  const int tid = threadIdx.x;
  const int lane = tid & 63, wv = tid >> 6;
  const int lt = blockIdx.x, h = blockIdx.y, b = blockIdx.z;
  const int l0 = lt * 32;
  const unsigned short* ap = attn + ((size_t)(b * NH + h) * NL + l0) * NT;
  const unsigned short* vp = vT + (size_t)(b * NH + h) * ND * NT;
  f32x4 acc[4] = {};
  const int arow = wv * 16 + (lane & 15);
  const int kg = (lane >> 4) * 8;
  const int bn = lane & 15;

  for (int kt = 0; kt < 8; ++kt) {  // k(t)-tiles of 128
    __syncthreads();
#pragma unroll
    for (int r = 0; r < 8; ++r) {   // stage 64 d x 128 t bf16
      int c = tid + r * 128;
      int d = c >> 4, tl = (c & 15) * 8;
      *(ushort8*)&vS[d][tl] = *(const ushort8*)(vp + (size_t)d * NT + kt * 128 + tl);
    }
    __syncthreads();
#pragma unroll
    for (int ks = 0; ks < 4; ++ks) {  // K=32 steps
      short8 af = *(const short8*)(ap + (size_t)arow * NT + kt * 128 + ks * 32 + kg);
#pragma unroll
      for (int dt = 0; dt < 4; ++dt) {
        short8 bf = *(const short8*)&vS[dt * 16 + bn][ks * 32 + kg];
        acc[dt] = __builtin_amdgcn_mfma_f32_16x16x32_bf16(af, bf, acc[dt], 0, 0, 0);
      }
    }
  }
  // write x as bf16 in (B, L, H*D) layout so proj's A is k-contiguous
  const int crow0 = wv * 16 + (lane >> 4) * 4;
#pragma unroll
  for (int dt = 0; dt < 4; ++dt) {
#pragma unroll
    for (int r = 0; r < 4; ++r) {
      int row = l0 + crow0 + r;
      xb[((size_t)b * NL + row) * DIM + h * ND + dt * 16 + bn] = f2bf(acc[dt][r]);
    }
  }
}

// ---------------------------------------------------------------------------
// K3: out[n,o] = sum_k x[n,k] * proj_w[o,k] + proj_b[o], bf16 MFMA, f32 out.
// proj_w is [o][k] row-major == B^T, so B-fragment needs no transpose.
// ---------------------------------------------------------------------------
__global__ __launch_bounds__(256) void k_proj(
    const unsigned short* __restrict__ xb, const float* __restrict__ pw,
    const float* __restrict__ pb, float* __restrict__ out)
{
  __shared__ unsigned short wS[64][136];
  const int tid = threadIdx.x;
  const int lane = tid & 63, wv = tid >> 6;
  const int n0 = blockIdx.x * 64, o0 = blockIdx.y * 64;
  f32x4 acc[4] = {};
  const int kg = (lane >> 4) * 8;
  const int bn = lane & 15;
  const int arow = n0 + wv * 16 + bn;

  for (int kt = 0; kt < 6; ++kt) {  // k-tiles of 128 (768 total)
    __syncthreads();
#pragma unroll
    for (int r = 0; r < 4; ++r) {   // stage W tile 64 o x 128 k as bf16
      int c = tid + r * 256;
      int oi = c >> 4, kl = (c & 15) * 8;
      const float* wp = pw + (size_t)(o0 + oi) * DIM + kt * 128 + kl;
      float4 x0 = *(const float4*)(wp);
      float4 x1 = *(const float4*)(wp + 4);
      ushort8 u;
      u[0] = f2bf(x0.x); u[1] = f2bf(x0.y); u[2] = f2bf(x0.z); u[3] = f2bf(x0.w);
      u[4] = f2bf(x1.x); u[5] = f2bf(x1.y); u[6] = f2bf(x1.z); u[7] = f2bf(x1.w);
      *(ushort8*)&wS[oi][kl] = u;
    }
    __syncthreads();
#pragma unroll
    for (int ks = 0; ks < 4; ++ks) {
      short8 af = *(const short8*)(xb + (size_t)arow * DIM + kt * 128 + ks * 32 + kg);
#pragma unroll
      for (int ot = 0; ot < 4; ++ot) {
        short8 bf = *(const short8*)&wS[ot * 16 + bn][ks * 32 + kg];
        acc[ot] = __builtin_amdgcn_mfma_f32_16x16x32_bf16(af, bf, acc[ot], 0, 0, 0);
      }
    }
  }
  const int crow0 = wv * 16 + (lane >> 4) * 4;
#pragma unroll
  for (int ot = 0; ot < 4; ++ot) {
    const int oc = o0 + ot * 16 + bn;
    const float bias = pb[oc];
#pragma unroll
    for (int r = 0; r < 4; ++r) {
      int row = n0 + crow0 + r;
      out[(size_t)row * DIM + oc] = acc[ot][r] + bias;
    }
  }
}

extern "C" void kernel_launch(void* const* d_in, const int* in_sizes, int n_in,
                              void* d_out, int out_size, void* d_ws, size_t ws_size,
                              hipStream_t stream) {
  const float* s0 = (const float*)d_in[0];
  const float* s1 = (const float*)d_in[1];
  const float* s2 = (const float*)d_in[2];
  const float* v  = (const float*)d_in[3];
  const float* fw = (const float*)d_in[4];
  // d_in[5] = fuse_b: unused — softmax is invariant to a per-row additive bias
  const float* pw = (const float*)d_in[6];
  const float* pb = (const float*)d_in[7];
  float* out = (float*)d_out;

  // workspace layout (bytes): attn bf16 50,331,648 | vT bf16 3,145,728 | xb bf16 3,145,728
  const size_t attn_bytes = (size_t)NB * NH * NL * NT * 2;
  const size_t vT_bytes   = (size_t)NB * NH * ND * NT * 2;
  unsigned short* attn = (unsigned short*)d_ws;
  unsigned short* vT   = (unsigned short*)((char*)d_ws + attn_bytes);
  unsigned short* xb   = (unsigned short*)((char*)d_ws + attn_bytes + vT_bytes);

  k_fuse_softmax<<<dim3(NB * NL), dim3(256), 0, stream>>>(s0, s1, s2, fw, attn);
  k_transpose_v<<<dim3(8, NH, NB), dim3(256), 0, stream>>>(v, vT);
  k_pv<<<dim3(32, NH, NB), dim3(128), 0, stream>>>(attn, vT, xb);
  k_proj<<<dim3(32, DIM / 64), dim3(256), 0, stream>>>(xb, pw, pb, out);
}

// Round 3
// 114.256 us; speedup vs baseline: 1.1065x; 1.1065x over previous
//
#include <hip/hip_runtime.h>
#include <hip/hip_bf16.h>

typedef __attribute__((ext_vector_type(8))) short short8;
typedef __attribute__((ext_vector_type(8))) unsigned short ushort8;
typedef __attribute__((ext_vector_type(4))) unsigned short u16x4;  // NOT "ushort4": HIP predefines that type
typedef __attribute__((ext_vector_type(4))) float f32x4;

#define NB 2
#define NH 12
#define NL 1024
#define NT 1024
#define ND 64
#define NCH 36
#define DIM 768

// round-to-nearest-even f32 -> bf16 bits (inputs finite; no NaN handling needed)
static __device__ __forceinline__ unsigned short f2bf(float x) {
  union { float f; unsigned int u; } c; c.f = x;
  unsigned int r = c.u + 0x7fffu + ((c.u >> 16) & 1u);
  return (unsigned short)(r >> 16);
}

// ---------------------------------------------------------------------------
// K1: channel-fuse (36 -> 12) + softmax over T, write attn as bf16.
// One block per (b, l): every score element is read exactly once.
// fuse_b is intentionally ignored: softmax(x + c) == softmax(x) for a
// per-row constant c (fuse_b[o] is constant over the softmax axis t).
//
// R1 -> R2: dropped the 48 KiB fused[12][1024] LDS buffer (it capped
// occupancy at 3 blocks/CU = 20.6% -> latency-bound at 1.5 TB/s). Softmax
// is now done fully in registers: wave shfl_xor reduce + 2x tiny LDS
// cross-wave combine. __launch_bounds__(256,4) -> 4 waves/SIMD target.
// ---------------------------------------------------------------------------
__global__ __launch_bounds__(256, 4) void k_fuse_softmax(
    const float* __restrict__ s0, const float* __restrict__ s1,
    const float* __restrict__ s2, const float* __restrict__ fw,
    unsigned short* __restrict__ attn)
{
  __shared__ float wS[NCH][16];     // wS[c][h] = fuse_w[h][c]; row padded to 64B
  __shared__ float red[2][4][NH];   // [max/sum][wave][head]
  const int tid = threadIdx.x;
  const int b = blockIdx.x >> 10;
  const int l = blockIdx.x & 1023;
  const int wv = tid >> 6, lane = tid & 63;

  for (int i = tid; i < NCH * NH; i += 256) {
    int h = i % NH, c = i / NH;
    wS[c][h] = fw[h * NCH + c];
  }
  __syncthreads();

  float acc[NH][4];
#pragma unroll
  for (int h = 0; h < NH; ++h) {
    acc[h][0] = 0.f; acc[h][1] = 0.f; acc[h][2] = 0.f; acc[h][3] = 0.f;
  }

  const int t0 = tid * 4;  // each thread owns 4 contiguous t
  const size_t base = (size_t)b * NH * NL * NT + (size_t)l * NT + t0;
  const float* ps[3] = { s0 + base, s1 + base, s2 + base };
#pragma unroll
  for (int g = 0; g < 3; ++g) {
    const float* p = ps[g];
#pragma unroll
    for (int ch = 0; ch < NH; ++ch) {
      float4 sv = *(const float4*)(p + (size_t)ch * NL * NT);
      float wreg[NH];
      *(float4*)&wreg[0] = *(const float4*)&wS[g * NH + ch][0];
      *(float4*)&wreg[4] = *(const float4*)&wS[g * NH + ch][4];
      *(float4*)&wreg[8] = *(const float4*)&wS[g * NH + ch][8];
#pragma unroll
      for (int h = 0; h < NH; ++h) {
        acc[h][0] = fmaf(wreg[h], sv.x, acc[h][0]);
        acc[h][1] = fmaf(wreg[h], sv.y, acc[h][1]);
        acc[h][2] = fmaf(wreg[h], sv.z, acc[h][2]);
        acc[h][3] = fmaf(wreg[h], sv.w, acc[h][3]);
      }
    }
  }

  // --- block-wide max per head (in registers) ---
  float mx[NH];
#pragma unroll
  for (int h = 0; h < NH; ++h) {
    mx[h] = fmaxf(fmaxf(acc[h][0], acc[h][1]), fmaxf(acc[h][2], acc[h][3]));
#pragma unroll
    for (int off = 32; off > 0; off >>= 1)
      mx[h] = fmaxf(mx[h], __shfl_xor(mx[h], off));
  }
  if (lane == 0) {
#pragma unroll
    for (int h = 0; h < NH; ++h) red[0][wv][h] = mx[h];
  }
  __syncthreads();
#pragma unroll
  for (int h = 0; h < NH; ++h)
    mx[h] = fmaxf(fmaxf(red[0][0][h], red[0][1][h]),
                  fmaxf(red[0][2][h], red[0][3][h]));

  // --- exp + block-wide sum per head ---
  float sm[NH];
#pragma unroll
  for (int h = 0; h < NH; ++h) {
    acc[h][0] = __expf(acc[h][0] - mx[h]);
    acc[h][1] = __expf(acc[h][1] - mx[h]);
    acc[h][2] = __expf(acc[h][2] - mx[h]);
    acc[h][3] = __expf(acc[h][3] - mx[h]);
    sm[h] = (acc[h][0] + acc[h][1]) + (acc[h][2] + acc[h][3]);
#pragma unroll
    for (int off = 32; off > 0; off >>= 1)
      sm[h] += __shfl_xor(sm[h], off);
  }
  if (lane == 0) {
#pragma unroll
    for (int h = 0; h < NH; ++h) red[1][wv][h] = sm[h];
  }
  __syncthreads();

#pragma unroll
  for (int h = 0; h < NH; ++h) {
    float s = (red[1][0][h] + red[1][1][h]) + (red[1][2][h] + red[1][3][h]);
    float inv = 1.0f / s;
    u16x4 u;
    u[0] = f2bf(acc[h][0] * inv);
    u[1] = f2bf(acc[h][1] * inv);
    u[2] = f2bf(acc[h][2] * inv);
    u[3] = f2bf(acc[h][3] * inv);
    *(u16x4*)(attn + ((size_t)(b * NH + h) * NL + l) * NT + t0) = u;
  }
}

// ---------------------------------------------------------------------------
// K2a: v (B,H,T,D) f32  ->  vT (B,H,D,T) bf16, via LDS tile transpose.
// Makes the PV B-fragment a contiguous-k 16B load.
// ---------------------------------------------------------------------------
__global__ __launch_bounds__(256) void k_transpose_v(
    const float* __restrict__ v, unsigned short* __restrict__ vT)
{
  __shared__ float vS[128][65];  // +1 pad breaks column-read conflicts
  const int tid = threadIdx.x;
  const int tt = blockIdx.x;   // t-tile of 128
  const int h = blockIdx.y, b = blockIdx.z;
  const int t0 = tt * 128;
  const float* vp = v + ((size_t)(b * NH + h) * NT + t0) * ND;
#pragma unroll
  for (int r = 0; r < 8; ++r) {
    int f = tid + r * 256;            // 2048 float4 chunks
    int t = f >> 4, d4 = (f & 15) * 4;
    float4 x = *(const float4*)(vp + (size_t)t * ND + d4);
    vS[t][d4 + 0] = x.x; vS[t][d4 + 1] = x.y;
    vS[t][d4 + 2] = x.z; vS[t][d4 + 3] = x.w;
  }
  __syncthreads();
  unsigned short* op = vT + (size_t)(b * NH + h) * ND * NT;
#pragma unroll
  for (int r = 0; r < 4; ++r) {
    int c = tid + r * 256;            // 1024 ushort8 chunks
    int d = c >> 4, tl = (c & 15) * 8;
    ushort8 u;
#pragma unroll
    for (int j = 0; j < 8; ++j) u[j] = f2bf(vS[tl + j][d]);
    *(ushort8*)(op + (size_t)d * NT + t0 + tl) = u;
  }
}

// ---------------------------------------------------------------------------
// K2: PV GEMM  x[b,h,l,:] = attn[b,h,l,:] @ v[b,h,:,:]  via bf16 MFMA.
// MFMA 16x16x32 fragment layout (verified passing in R1):
//   A: row = lane&15, k = 8*(lane>>4)+e   (e=0..7, one 16B load)
//   B: col = lane&15, k = 8*(lane>>4)+e   (16B from k-contiguous vT row)
//   C/D: col = lane&15, row = (lane>>4)*4 + reg   [measured m89/m91]
// LDS vS stride 136 ushorts: conflict-free (SQ_LDS_BANK_CONFLICT==0 in R1).
// ---------------------------------------------------------------------------
__global__ __launch_bounds__(128) void k_pv(
    const unsigned short* __restrict__ attn,
    const unsigned short* __restrict__ vT,
    unsigned short* __restrict__ xb)
{
  __shared__ unsigned short vS[64][136];
  const int tid = threadIdx.x;
  const int lane = tid & 63, wv = tid >> 6;
  const int lt = blockIdx.x, h = blockIdx.y, b = blockIdx.z;
  const int l0 = lt * 32;
  const unsigned short* ap = attn + ((size_t)(b * NH + h) * NL + l0) * NT;
  const unsigned short* vp = vT + (size_t)(b * NH + h) * ND * NT;
  f32x4 acc[4] = {};
  const int arow = wv * 16 + (lane & 15);
  const int kg = (lane >> 4) * 8;
  const int bn = lane & 15;

  for (int kt = 0; kt < 8; ++kt) {  // k(t)-tiles of 128
    __syncthreads();
#pragma unroll
    for (int r = 0; r < 8; ++r) {   // stage 64 d x 128 t bf16
      int c = tid + r * 128;
      int d = c >> 4, tl = (c & 15) * 8;
      *(ushort8*)&vS[d][tl] = *(const ushort8*)(vp + (size_t)d * NT + kt * 128 + tl);
    }
    __syncthreads();
#pragma unroll
    for (int ks = 0; ks < 4; ++ks) {  // K=32 steps
      short8 af = *(const short8*)(ap + (size_t)arow * NT + kt * 128 + ks * 32 + kg);
#pragma unroll
      for (int dt = 0; dt < 4; ++dt) {
        short8 bf = *(const short8*)&vS[dt * 16 + bn][ks * 32 + kg];
        acc[dt] = __builtin_amdgcn_mfma_f32_16x16x32_bf16(af, bf, acc[dt], 0, 0, 0);
      }
    }
  }
  // write x as bf16 in (B, L, H*D) layout so proj's A is k-contiguous
  const int crow0 = wv * 16 + (lane >> 4) * 4;
#pragma unroll
  for (int dt = 0; dt < 4; ++dt) {
#pragma unroll
    for (int r = 0; r < 4; ++r) {
      int row = l0 + crow0 + r;
      xb[((size_t)b * NL + row) * DIM + h * ND + dt * 16 + bn] = f2bf(acc[dt][r]);
    }
  }
}

// ---------------------------------------------------------------------------
// K3: out[n,o] = sum_k x[n,k] * proj_w[o,k] + proj_b[o], bf16 MFMA, f32 out.
// proj_w is [o][k] row-major == B^T, so B-fragment needs no transpose.
// ---------------------------------------------------------------------------
__global__ __launch_bounds__(256) void k_proj(
    const unsigned short* __restrict__ xb, const float* __restrict__ pw,
    const float* __restrict__ pb, float* __restrict__ out)
{
  __shared__ unsigned short wS[64][136];
  const int tid = threadIdx.x;
  const int lane = tid & 63, wv = tid >> 6;
  const int n0 = blockIdx.x * 64, o0 = blockIdx.y * 64;
  f32x4 acc[4] = {};
  const int kg = (lane >> 4) * 8;
  const int bn = lane & 15;
  const int arow = n0 + wv * 16 + bn;

  for (int kt = 0; kt < 6; ++kt) {  // k-tiles of 128 (768 total)
    __syncthreads();
#pragma unroll
    for (int r = 0; r < 4; ++r) {   // stage W tile 64 o x 128 k as bf16
      int c = tid + r * 256;
      int oi = c >> 4, kl = (c & 15) * 8;
      const float* wp = pw + (size_t)(o0 + oi) * DIM + kt * 128 + kl;
      float4 x0 = *(const float4*)(wp);
      float4 x1 = *(const float4*)(wp + 4);
      ushort8 u;
      u[0] = f2bf(x0.x); u[1] = f2bf(x0.y); u[2] = f2bf(x0.z); u[3] = f2bf(x0.w);
      u[4] = f2bf(x1.x); u[5] = f2bf(x1.y); u[6] = f2bf(x1.z); u[7] = f2bf(x1.w);
      *(ushort8*)&wS[oi][kl] = u;
    }
    __syncthreads();
#pragma unroll
    for (int ks = 0; ks < 4; ++ks) {
      short8 af = *(const short8*)(xb + (size_t)arow * DIM + kt * 128 + ks * 32 + kg);
#pragma unroll
      for (int ot = 0; ot < 4; ++ot) {
        short8 bf = *(const short8*)&wS[ot * 16 + bn][ks * 32 + kg];
        acc[ot] = __builtin_amdgcn_mfma_f32_16x16x32_bf16(af, bf, acc[ot], 0, 0, 0);
      }
    }
  }
  const int crow0 = wv * 16 + (lane >> 4) * 4;
#pragma unroll
  for (int ot = 0; ot < 4; ++ot) {
    const int oc = o0 + ot * 16 + bn;
    const float bias = pb[oc];
#pragma unroll
    for (int r = 0; r < 4; ++r) {
      int row = n0 + crow0 + r;
      out[(size_t)row * DIM + oc] = acc[ot][r] + bias;
    }
  }
}

extern "C" void kernel_launch(void* const* d_in, const int* in_sizes, int n_in,
                              void* d_out, int out_size, void* d_ws, size_t ws_size,
                              hipStream_t stream) {
  const float* s0 = (const float*)d_in[0];
  const float* s1 = (const float*)d_in[1];
  const float* s2 = (const float*)d_in[2];
  const float* v  = (const float*)d_in[3];
  const float* fw = (const float*)d_in[4];
  // d_in[5] = fuse_b: unused — softmax is invariant to a per-row additive bias
  const float* pw = (const float*)d_in[6];
  const float* pb = (const float*)d_in[7];
  float* out = (float*)d_out;

  // workspace layout (bytes): attn bf16 50,331,648 | vT bf16 3,145,728 | xb bf16 3,145,728
  const size_t attn_bytes = (size_t)NB * NH * NL * NT * 2;
  const size_t vT_bytes   = (size_t)NB * NH * ND * NT * 2;
  unsigned short* attn = (unsigned short*)d_ws;
  unsigned short* vT   = (unsigned short*)((char*)d_ws + attn_bytes);
  unsigned short* xb   = (unsigned short*)((char*)d_ws + attn_bytes + vT_bytes);

  k_fuse_softmax<<<dim3(NB * NL), dim3(256), 0, stream>>>(s0, s1, s2, fw, attn);
  k_transpose_v<<<dim3(8, NH, NB), dim3(256), 0, stream>>>(v, vT);
  k_pv<<<dim3(32, NH, NB), dim3(128), 0, stream>>>(attn, vT, xb);
  k_proj<<<dim3(32, DIM / 64), dim3(256), 0, stream>>>(xb, pw, pb, out);
}